// Round 2
// 424.830 us; speedup vs baseline: 1.0658x; 1.0658x over previous
//
#include <hip/hip_runtime.h>
#include <math.h>

#define PI_F 3.14159265358979323846f

typedef __attribute__((ext_vector_type(8))) short  short8;   // 8 bf16 = 4 VGPRs (MFMA A/B frag)
typedef __attribute__((ext_vector_type(4))) float  floatx4;  // MFMA C/D frag

constexpr int E = 512;
constexpr int Q = 64;
constexpr int NCHUNK = E / 32;                 // 16 K-chunks for 16x16x32
constexpr int WS_B_ENTRIES = NCHUNK * 12 * 64; // 12288 16-B fragments (Wr|Wi|Wp1)
constexpr int WS_P2_OFF = WS_B_ENTRIES;        // then 2*4*64 = 512 fragments (Wp2)
constexpr int CHUNK_BYTES = 12 * 64 * 16;      // 12288 B of B-frags per K-chunk

__device__ __forceinline__ unsigned short bf16_rne(float x) {
    unsigned u = __float_as_uint(x);
    unsigned r = u + 0x7fffu + ((u >> 16) & 1u);
    return (unsigned short)(r >> 16);
}

// split fp32 -> hi bf16 + lo bf16 (residual); A_hi*B + A_lo*B recovers ~fp32 A precision
__device__ __forceinline__ void split_bf16_8(const float* v, short8& hi, short8& lo) {
    #pragma unroll
    for (int j = 0; j < 8; ++j) {
        unsigned u  = __float_as_uint(v[j]);
        unsigned rh = (u + 0x7fffu + ((u >> 16) & 1u)) & 0xffff0000u;
        hi[j] = (short)(rh >> 16);
        float res = v[j] - __uint_as_float(rh);
        lo[j] = (short)bf16_rne(res);
    }
}

__device__ __forceinline__ float tanh_fast(float x) {
    const float xc = fminf(fmaxf(x, -15.f), 15.f);
    const float e  = __expf(2.f * xc);
    return (e - 1.f) / (e + 1.f);
}

// async 16-B global->LDS copy (gfx950 global_load_lds_dwordx4)
// HW semantics: LDS dest = wave-uniform base (first lane) + lane*16; our
// per-lane pointers are exactly base+lane*16 (linear), so this is exact.
__device__ __forceinline__ void async_copy16(const void* g, void* l) {
    __builtin_amdgcn_global_load_lds(
        (const __attribute__((address_space(1))) unsigned int*)g,
        (__attribute__((address_space(3))) unsigned int*)l, 16, 0, 0);
}

// ---- pack weights (fp32) into bf16 MFMA B-fragment order in d_ws ----
// B frag for 16x16x32: lane L holds B[k = kbase + (L>>4)*8 + j][n = tile*16 + (L&15)]
// frag index: (c*12 + mat*4 + tt)*64 + L  for the three E->Q mats; then Wp2 frags.
__global__ void prep_weights(const float* __restrict__ Wr, const float* __restrict__ Wi,
                             const float* __restrict__ Wp1, const float* __restrict__ Wp2,
                             short* __restrict__ ws)
{
    const int e = blockIdx.x * 256 + threadIdx.x;   // grid sized exactly
    const float* W;
    int kbase, n;
    if (e < WS_B_ENTRIES) {
        const int L = e & 63;
        const int f = e >> 6;          // 0..191
        const int tt = f & 3;
        const int g  = f >> 2;         // 0..47
        const int m  = g % 3, c = g / 3;
        W = (m == 0) ? Wr : (m == 1) ? Wi : Wp1;
        n     = tt * 16 + (L & 15);
        kbase = c * 32 + (L >> 4) * 8;
    } else {
        const int e2 = e - WS_B_ENTRIES;   // 0..511
        const int L  = e2 & 63;
        const int tt = (e2 >> 6) & 3;
        const int c2 = e2 >> 8;
        W = Wp2;
        n     = tt * 16 + (L & 15);
        kbase = c2 * 32 + (L >> 4) * 8;
    }
    short8 frag;
    #pragma unroll
    for (int j = 0; j < 8; ++j)
        frag[j] = (short)bf16_rne(W[(kbase + j) * Q + n]);
    *(short8*)(ws + (size_t)e * 8) = frag;
}

__global__ __launch_bounds__(256, 4)
void qi_mfma(const float* __restrict__ feat, const short* __restrict__ wsb,
             const float* __restrict__ br,  const float* __restrict__ bi,
             const float* __restrict__ bp1, const float* __restrict__ bp2,
             const float* __restrict__ op_p,
             float* __restrict__ out, long long nrows)
{
    // Staging buffers for weight B-frags (main loop) union'd with the tanh(p1)
    // scratch (used only after the main loop; the loop's final barrier makes
    // the reuse safe). 24576 B total -> LDS allows 6 blocks/CU.
    // alignas(16): the B-frag path does ds_read_b128 through short8*.
    __shared__ alignas(16) union {
        short wbuf[2][CHUNK_BYTES / 2];   // 2 x 12 KB double-buffered frags
        float tp[4][16][68];              // 17408 B; stride 68 -> free 2-way conflicts
    } sh;

    const int tid = threadIdx.x;
    const int L   = tid & 63;
    const int wv  = tid >> 6;
    const int l15 = L & 15;
    const int q4  = L >> 4;                       // quad id
    const long long rowBase = (long long)blockIdx.x * 64 + wv * 16;

    // A gather: lane reads rows rowBase+l15, k = c*32 + q4*8 + [0..7]
    const float* aptr = feat + (rowBase + l15) * (long long)E + q4 * 8;

    // ---- prologue: stage chunk 0 into wbuf[0]; prefetch features chunk 0 ----
    {
        const char* g = (const char*)wsb + (size_t)tid * 16;
        char*       l = (char*)sh.wbuf[0] + (size_t)tid * 16;
        #pragma unroll
        for (int r = 0; r < 3; ++r) async_copy16(g + r * 4096, l + r * 4096);
    }
    floatx4 a0 = *(const floatx4*)aptr;
    floatx4 a1 = *(const floatx4*)(aptr + 4);

    floatx4 acc[12];
    #pragma unroll
    for (int t = 0; t < 12; ++t) acc[t] = (floatx4){0.f, 0.f, 0.f, 0.f};

    __syncthreads();   // vmcnt(0) drain: chunk-0 stage + feature prefetch landed

    // ---- 2-phase main loop: stage c+1 || compute c; one barrier per chunk ----
    int cur = 0;
    for (int c = 0; c < NCHUNK; ++c) {
        floatx4 n0, n1;
        const bool has_next = (c + 1 < NCHUNK);
        if (has_next) {
            const char* g = (const char*)wsb + (size_t)(c + 1) * CHUNK_BYTES + (size_t)tid * 16;
            char*       l = (char*)sh.wbuf[cur ^ 1] + (size_t)tid * 16;
            #pragma unroll
            for (int r = 0; r < 3; ++r) async_copy16(g + r * 4096, l + r * 4096);
            n0 = *(const floatx4*)(aptr + (c + 1) * 32);
            n1 = *(const floatx4*)(aptr + (c + 1) * 32 + 4);
        }

        float av[8];
        #pragma unroll
        for (int j = 0; j < 4; ++j) { av[j] = a0[j]; av[4 + j] = a1[j]; }
        short8 ah, al;
        split_bf16_8(av, ah, al);

        // B-frags from LDS: lane L reads 16 B at (mt*64+L)*16 -> conflict-free b128
        const short8* wl = (const short8*)sh.wbuf[cur];
        #pragma unroll
        for (int mt = 0; mt < 12; ++mt) {
            const short8 bf = wl[mt * 64 + L];
            acc[mt] = __builtin_amdgcn_mfma_f32_16x16x32_bf16(ah, bf, acc[mt], 0, 0, 0);
            acc[mt] = __builtin_amdgcn_mfma_f32_16x16x32_bf16(al, bf, acc[mt], 0, 0, 0);
        }

        // barrier: (a) all waves done reading wbuf[cur] before it's re-staged,
        // (b) vmcnt(0) -> stage of c+1 and feature prefetch complete.
        __syncthreads();
        if (has_next) { a0 = n0; a1 = n1; }
        cur ^= 1;
    }

    // ---- per-held-column constants (col = t*16 + l15) ----
    float brv[4], biv[4], bp1v[4], bp2v[4], pv[4], dcv[4];
    #pragma unroll
    for (int t = 0; t < 4; ++t) {
        const int colv = t * 16 + l15;
        brv[t] = br[colv]; biv[t] = bi[colv]; bp1v[t] = bp1[colv]; bp2v[t] = bp2[colv];
        const float p = op_p[colv];
        pv[t]  = p;
        dcv[t] = 1.f / (1.f + __expf(-p)) - p * p;   // sigmoid(p) - p^2 (diag correction)
    }

    // ---- activations; stage tanh(p1) for the Wp2 MFMA (C-layout -> LDS) ----
    // (safe to overwrite the union: final loop barrier above)
    float rv[4][4], iv[4][4];
    #pragma unroll
    for (int t = 0; t < 4; ++t)
        #pragma unroll
        for (int g = 0; g < 4; ++g) {
            rv[t][g] = tanh_fast(acc[t][g]     + brv[t]);
            iv[t][g] = tanh_fast(acc[4 + t][g] + biv[t]);
            sh.tp[wv][q4 * 4 + g][t * 16 + l15] = tanh_fast(acc[8 + t][g] + bp1v[t]);
        }
    __syncthreads();

    // ---- phase layer 2: P2 = tanh(Tp) @ Wp2 via split-A MFMA over K=64 ----
    const short8* wfrag = (const short8*)wsb;
    floatx4 accp2[4];
    #pragma unroll
    for (int t = 0; t < 4; ++t) accp2[t] = (floatx4){0.f, 0.f, 0.f, 0.f};
    #pragma unroll
    for (int c2 = 0; c2 < 2; ++c2) {
        float tv[8];
        {
            const floatx4 t0 = *(const floatx4*)&sh.tp[wv][l15][c2 * 32 + q4 * 8];
            const floatx4 t1 = *(const floatx4*)&sh.tp[wv][l15][c2 * 32 + q4 * 8 + 4];
            #pragma unroll
            for (int j = 0; j < 4; ++j) { tv[j] = t0[j]; tv[4 + j] = t1[j]; }
        }
        short8 th, tl;
        split_bf16_8(tv, th, tl);
        #pragma unroll
        for (int tt = 0; tt < 4; ++tt) {
            const short8 bf = wfrag[(size_t)(WS_P2_OFF + (c2 * 4 + tt) * 64 + L)];
            accp2[tt] = __builtin_amdgcn_mfma_f32_16x16x32_bf16(th, bf, accp2[tt], 0, 0, 0);
            accp2[tt] = __builtin_amdgcn_mfma_f32_16x16x32_bf16(tl, bf, accp2[tt], 0, 0, 0);
        }
    }

    float* __restrict__ outR = out;
    float* __restrict__ outI = out +       nrows * Q;
    float* __restrict__ outP = out + 2LL * nrows * Q;

    // ---- phases, rotation; store phases now to free registers ----
    float rp[4][4], ip[4][4];
    #pragma unroll
    for (int t = 0; t < 4; ++t)
        #pragma unroll
        for (int g = 0; g < 4; ++g) {
            const float ph = tanh_fast(accp2[t][g] + bp2v[t]) * PI_F;
            const long long row = rowBase + q4 * 4 + g;
            outP[row * Q + t * 16 + l15] = ph;
            const float si = __sinf(ph), co = __cosf(ph);
            rp[t][g] = rv[t][g] * co - iv[t][g] * si;
            ip[t][g] = rv[t][g] * si + iv[t][g] * co;
        }

    // ---- per-row normalization + structured Hermitian operator ----
    // row of lane = q4*4+g; its 64 cols live in this quad's 16 lanes x 4 tiles
    #pragma unroll
    for (int g = 0; g < 4; ++g) {
        float n2 = 0.f;
        #pragma unroll
        for (int t = 0; t < 4; ++t) n2 += rp[t][g] * rp[t][g] + ip[t][g] * ip[t][g];
        #pragma unroll
        for (int off = 1; off <= 8; off <<= 1) n2 += __shfl_xor(n2, off);  // intra-quad reduce
        const float inv = 1.f / sqrtf(n2 + 1e-12f);

        float dR = 0.f, dI = 0.f, sR = 0.f, sI = 0.f;
        #pragma unroll
        for (int t = 0; t < 4; ++t) {
            rp[t][g] *= inv; ip[t][g] *= inv;        // rn, inn
            dR += rp[t][g] * pv[t];  dI += ip[t][g] * pv[t];
            sR += rp[t][g];          sI += ip[t][g];
        }
        #pragma unroll
        for (int off = 1; off <= 8; off <<= 1) {
            dR += __shfl_xor(dR, off); dI += __shfl_xor(dI, off);
            sR += __shfl_xor(sR, off); sI += __shfl_xor(sI, off);
        }

        const long long row = rowBase + q4 * 4 + g;
        #pragma unroll
        for (int t = 0; t < 4; ++t) {
            const long long o = row * Q + t * 16 + l15;
            // (x@R)_j = (x.p)p_j + x_j(sig_j - p_j^2);  (x@I)_j = (x.p) - (sum x) p_j
            outR[o] = dR * pv[t] + rp[t][g] * dcv[t] - dI + sI * pv[t];
            outI[o] = dR - sR * pv[t] + ip[t][g] * dcv[t] + dI * pv[t];
        }
    }
}

extern "C" void kernel_launch(void* const* d_in, const int* in_sizes, int n_in,
                              void* d_out, int out_size, void* d_ws, size_t ws_size,
                              hipStream_t stream) {
    const float* feat = (const float*)d_in[0];
    const float* Wr   = (const float*)d_in[1];
    const float* br   = (const float*)d_in[2];
    const float* Wi   = (const float*)d_in[3];
    const float* bi   = (const float*)d_in[4];
    const float* Wp1  = (const float*)d_in[5];
    const float* bp1  = (const float*)d_in[6];
    const float* Wp2  = (const float*)d_in[7];
    const float* bp2  = (const float*)d_in[8];
    const float* opp  = (const float*)d_in[9];

    short* ws = (short*)d_ws;   // needs (12288+512)*16 = 200 KB

    const long long nrows = (long long)in_sizes[0] / E;   // 131072
    const int blocks = (int)(nrows / 64);                 // 2048

    hipLaunchKernelGGL(prep_weights, dim3((WS_B_ENTRIES + 512) / 256), dim3(256), 0, stream,
                       Wr, Wi, Wp1, Wp2, ws);
    hipLaunchKernelGGL(qi_mfma, dim3(blocks), dim3(256), 0, stream,
                       feat, ws, br, bi, bp1, bp2, opp, (float*)d_out, nrows);
}